// Round 5
// baseline (435.493 us; speedup 1.0000x reference)
//
#include <hip/hip_runtime.h>
#include <hip/hip_bf16.h>
#include <stdint.h>

#define NN 50000
#define RR 5
#define AA 8
#define FF 128
#define TT 2
#define OO 128
#define KDIM 1024   // A*F
#define NCOLS 2048  // 8 rotations * T * O
#define RA 40       // R*A

typedef __attribute__((ext_vector_type(8))) short short8;
typedef __attribute__((ext_vector_type(4))) float f32x4;
typedef __attribute__((ext_vector_type(4))) int i32x4;

__device__ inline void gload_lds16(const void* g, void* l) {
  __builtin_amdgcn_global_load_lds(
      (const __attribute__((address_space(1))) unsigned int*)g,
      (__attribute__((address_space(3))) unsigned int*)l, 16, 0, 0);
}

// ---------- prep: mesh->bf16 sliced, C2, BmatT, packed bary ----------
__global__ void prep_kernel(const float* __restrict__ mesh,
                            const float* __restrict__ coeffs,
                            const float* __restrict__ W,
                            const float* __restrict__ bary_w,
                            const int* __restrict__ bary_idx,
                            __hip_bfloat16* __restrict__ meshq,  // [4][N][32]
                            float* __restrict__ C2,
                            __hip_bfloat16* __restrict__ BmatT,
                            unsigned* __restrict__ packb,
                            int do_pack) {
  int tid = blockIdx.x * blockDim.x + threadIdx.x;
  int stride = gridDim.x * blockDim.x;
  for (int i = tid; i < NN * FF; i += stride) {
    int n = i >> 7, f = i & 127;
    int p = f >> 5, fo = f & 31;
    meshq[((long)p * NN + n) * 32 + fo] = __float2bfloat16(mesh[i]);
  }
  for (int i = tid; i < AA * RA; i += stride) {
    int a = i / RA, k = i % RA;
    float s = 0.f;
    for (int r = 0; r < RR; ++r) s += coeffs[(r * AA + a) * RA + k];
    C2[i] = s;
  }
  for (int i = tid; i < NCOLS * KDIM; i += stride) {
    int c = i >> 10, kf = i & 1023;
    int kr = c >> 8, t = (c >> 7) & 1, o = c & 127;
    int a = kf >> 7, f = kf & 127;
    int arot = (a + kr) & 7;
    BmatT[i] = __float2bfloat16(W[((arot * TT + t) * OO + o) * FF + f]);
  }
  if (do_pack) {
    for (int i = tid; i < NN * 120; i += stride) {
      __hip_bfloat16 h = __float2bfloat16(bary_w[i]);
      unsigned wb = *(unsigned short*)&h;
      packb[i] = ((unsigned)bary_idx[i] << 16) | wb;
    }
  }
}

// ---------- S pass (packed): gather 32-feature slice + C2 mixing ----------
__global__ __launch_bounds__(256) void s_pass_packed(
    const __hip_bfloat16* __restrict__ meshq,
    const unsigned* __restrict__ packb,
    const float* __restrict__ C2,
    __hip_bfloat16* __restrict__ Sout,
    int p) {
  __shared__ unsigned pk_s[16 * 120];
  __shared__ float c2_s[AA * RA];
  int tid = threadIdx.x;
  long n0 = (long)blockIdx.x * 16;
  const i32x4* psrc = (const i32x4*)(packb + n0 * 120);
  for (int i = tid; i < 480; i += 256) {
    i32x4 v = __builtin_nontemporal_load(psrc + i);
    ((i32x4*)pk_s)[i] = v;
  }
  for (int i = tid; i < AA * RA; i += 256) c2_s[i] = C2[i];
  __syncthreads();

  int g = tid >> 4;
  int fo = tid & 15;
  long n = n0 + g;
  const unsigned* pg = pk_s + g * 120;
  const char* mbase = (const char*)(meshq + (long)p * NN * 32) + fo * 4;

  float sx_acc[AA], sy_acc[AA];
#pragma unroll
  for (int a = 0; a < AA; ++a) { sx_acc[a] = 0.f; sy_acc[a] = 0.f; }

#pragma unroll 5
  for (int k = 0; k < RA; ++k) {
    float sx = 0.f, sy = 0.f;
#pragma unroll
    for (int j = 0; j < 3; ++j) {
      unsigned v = pg[k * 3 + j];
      unsigned row = v >> 16;
      float w = __uint_as_float(v << 16);
      unsigned u = *(const unsigned*)(mbase + (long)row * 64);
      sx += w * __uint_as_float(u << 16);
      sy += w * __uint_as_float(u & 0xffff0000u);
    }
#pragma unroll
    for (int a = 0; a < AA; ++a) {
      float c = c2_s[a * RA + k];
      sx_acc[a] += c * sx;
      sy_acc[a] += c * sy;
    }
  }

  long base = n * KDIM + p * 32 + fo * 2;
#pragma unroll
  for (int a = 0; a < AA; ++a) {
    __hip_bfloat16 hx = __float2bfloat16(sx_acc[a]);
    __hip_bfloat16 hy = __float2bfloat16(sy_acc[a]);
    unsigned u = (unsigned)*(unsigned short*)&hx | ((unsigned)*(unsigned short*)&hy << 16);
    __builtin_nontemporal_store(u, (unsigned*)(Sout + base + a * FF));
  }
}

// ---------- S pass (legacy fallback) ----------
__global__ __launch_bounds__(256) void s_pass_kernel(
    const __hip_bfloat16* __restrict__ meshq,
    const float* __restrict__ bary_w,
    const int* __restrict__ bary_idx,
    const float* __restrict__ C2,
    __hip_bfloat16* __restrict__ Sout,
    int p) {
  __shared__ float w_s[16 * 120];
  __shared__ int i_s[16 * 120];
  __shared__ float c2_s[AA * RA];
  int tid = threadIdx.x;
  long n0 = (long)blockIdx.x * 16;
  const f32x4* wsrc = (const f32x4*)(bary_w + n0 * 120);
  const i32x4* isrc = (const i32x4*)(bary_idx + n0 * 120);
  for (int i = tid; i < 480; i += 256) {
    f32x4 wv = __builtin_nontemporal_load(wsrc + i);
    ((f32x4*)w_s)[i] = wv;
    i32x4 iv = __builtin_nontemporal_load(isrc + i);
    ((i32x4*)i_s)[i] = iv;
  }
  for (int i = tid; i < AA * RA; i += 256) c2_s[i] = C2[i];
  __syncthreads();
  int g = tid >> 4;
  int fo = tid & 15;
  long n = n0 + g;
  const float* wg = w_s + g * 120;
  const int* ig = i_s + g * 120;
  const char* mbase = (const char*)(meshq + (long)p * NN * 32) + fo * 4;
  float sx_acc[AA], sy_acc[AA];
#pragma unroll
  for (int a = 0; a < AA; ++a) { sx_acc[a] = 0.f; sy_acc[a] = 0.f; }
#pragma unroll 5
  for (int k = 0; k < RA; ++k) {
    float sx = 0.f, sy = 0.f;
#pragma unroll
    for (int j = 0; j < 3; ++j) {
      int row = ig[k * 3 + j];
      unsigned u = *(const unsigned*)(mbase + (long)row * 64);
      float w = wg[k * 3 + j];
      sx += w * __uint_as_float(u << 16);
      sy += w * __uint_as_float(u & 0xffff0000u);
    }
#pragma unroll
    for (int a = 0; a < AA; ++a) {
      float c = c2_s[a * RA + k];
      sx_acc[a] += c * sx;
      sy_acc[a] += c * sy;
    }
  }
  long base = n * KDIM + p * 32 + fo * 2;
#pragma unroll
  for (int a = 0; a < AA; ++a) {
    __hip_bfloat16 hx = __float2bfloat16(sx_acc[a]);
    __hip_bfloat16 hy = __float2bfloat16(sy_acc[a]);
    unsigned u = (unsigned)*(unsigned short*)&hx | ((unsigned)*(unsigned short*)&hy << 16);
    __builtin_nontemporal_store(u, (unsigned*)(Sout + base + a * FF));
  }
}

// ---------- GEMM: 256x256 tile, 32 K-steps (BK=32), 4 LDS buffers,
// fine-grained 2-phase/K-step schedule with counted vmcnt (m201-style) ----------
// grid (8, 200): kr = by&7, mt = (by>>3)*8 + bx; 512 threads = 8 waves (2M x 4N)
__global__ __launch_bounds__(512, 1) void gemm_kernel(
    const __hip_bfloat16* __restrict__ Sm,
    const __hip_bfloat16* __restrict__ BT,
    const float* __restrict__ bias,
    float* __restrict__ out) {
  int bx = blockIdx.x;
  int by = blockIdx.y;
  int kr = by & 7;
  int mt = ((by >> 3) << 3) + bx;
  if (mt >= 196) return;
  int row0 = mt * 256;
  int col0 = kr * 256;

  int tid = threadIdx.x;
  int lane = tid & 63;
  int wid = tid >> 6;
  int wave_m = wid >> 2;   // 0..1
  int wave_n = wid & 3;    // 0..3

  // 4 buffers x (A 16KB + B 16KB). Row = 64B = 4 slots of 16B, slot ^= (r>>1)&3.
  __shared__ __align__(16) char lds[131072];

  // --- precomputed staging offsets (invariant except k0) ---
  long srcA[2], srcB[2];
  int dstA[2], dstB[2];
#pragma unroll
  for (int i = 0; i < 2; ++i) {
    int li = i * 512 + tid;
    int r = li >> 2, sp = li & 3;
    int sl = sp ^ ((r >> 1) & 3);
    int rowA = row0 + r;
    if (rowA >= NN) rowA = NN - 1;
    srcA[i] = (long)rowA * KDIM + sl * 8;
    dstA[i] = li * 16;
    srcB[i] = (long)(col0 + r) * KDIM + sl * 8;
    dstB[i] = 16384 + li * 16;
  }
  // --- fragment read offsets within a buffer ---
  int offA[8], offB[4];
#pragma unroll
  for (int m = 0; m < 8; ++m) {
    int r = wave_m * 128 + m * 16 + (lane & 15);
    int phys = (lane >> 4) ^ ((r >> 1) & 3);
    offA[m] = r * 64 + phys * 16;
  }
#pragma unroll
  for (int q = 0; q < 4; ++q) {
    int c = (q >> 1) * 128 + wave_n * 32 + (q & 1) * 16 + (lane & 15);
    int phys = (lane >> 4) ^ ((c >> 1) & 3);
    offB[q] = 16384 + c * 64 + phys * 16;
  }

  f32x4 acc[8][4];
#pragma unroll
  for (int m = 0; m < 8; ++m)
#pragma unroll
    for (int q = 0; q < 4; ++q) acc[m][q] = (f32x4){0.f, 0.f, 0.f, 0.f};

#define STAGE_A(T)                                                   \
  {                                                                  \
    int b_ = ((T) & 3) * 32768;                                      \
    long k0_ = (long)(T) * 32;                                       \
    _Pragma("unroll") for (int i_ = 0; i_ < 2; ++i_)                 \
        gload_lds16(Sm + srcA[i_] + k0_, lds + b_ + dstA[i_]);       \
  }
#define STAGE_B(T)                                                   \
  {                                                                  \
    int b_ = ((T) & 3) * 32768;                                      \
    long k0_ = (long)(T) * 32;                                       \
    _Pragma("unroll") for (int i_ = 0; i_ < 2; ++i_)                 \
        gload_lds16(BT + srcB[i_] + k0_, lds + b_ + dstB[i_]);       \
  }

  // prologue: steps 0..2 fully staged; A(3)/B(3) staged inside step 0
  STAGE_A(0) STAGE_B(0) STAGE_A(1) STAGE_B(1) STAGE_A(2) STAGE_B(2)

#define GSTEP(STP, VMSTR, DOSTAGE)                                            \
  {                                                                           \
    const char* cb = lds + ((STP) & 3) * 32768;                               \
    asm volatile("s_waitcnt " VMSTR ::: "memory");                            \
    __builtin_amdgcn_sched_barrier(0);                                        \
    __builtin_amdgcn_s_barrier();                                             \
    __builtin_amdgcn_sched_barrier(0);                                        \
    short8 aF[4], bF[4], aG[4];                                               \
    _Pragma("unroll") for (int m_ = 0; m_ < 4; ++m_)                          \
        aF[m_] = *(const short8*)(cb + offA[m_]);                             \
    _Pragma("unroll") for (int q_ = 0; q_ < 4; ++q_)                          \
        bF[q_] = *(const short8*)(cb + offB[q_]);                             \
    if (DOSTAGE) STAGE_A((STP) + 3)                                           \
    __builtin_amdgcn_s_setprio(1);                                            \
    _Pragma("unroll") for (int m_ = 0; m_ < 4; ++m_)                          \
        _Pragma("unroll") for (int q_ = 0; q_ < 4; ++q_)                      \
            acc[m_][q_] = __builtin_amdgcn_mfma_f32_16x16x32_bf16(            \
                aF[m_], bF[q_], acc[m_][q_], 0, 0, 0);                        \
    __builtin_amdgcn_s_setprio(0);                                            \
    __builtin_amdgcn_sched_barrier(0);                                        \
    __builtin_amdgcn_s_barrier();                                             \
    __builtin_amdgcn_sched_barrier(0);                                        \
    _Pragma("unroll") for (int m_ = 0; m_ < 4; ++m_)                          \
        aG[m_] = *(const short8*)(cb + offA[m_ + 4]);                         \
    if (DOSTAGE) STAGE_B((STP) + 3)                                           \
    __builtin_amdgcn_s_setprio(1);                                            \
    _Pragma("unroll") for (int m_ = 0; m_ < 4; ++m_)                          \
        _Pragma("unroll") for (int q_ = 0; q_ < 4; ++q_)                      \
            acc[m_ + 4][q_] = __builtin_amdgcn_mfma_f32_16x16x32_bf16(        \
                aG[m_], bF[q_], acc[m_ + 4][q_], 0, 0, 0);                    \
    __builtin_amdgcn_s_setprio(0);                                            \
    __builtin_amdgcn_sched_barrier(0);                                        \
  }

  for (int s = 0; s < 29; ++s) GSTEP(s, "vmcnt(8)", 1)
  GSTEP(29, "vmcnt(8)", 0)
  GSTEP(30, "vmcnt(4)", 0)
  GSTEP(31, "vmcnt(0)", 0)

  // epilogue: out[n][kr][o] = relu(z_t0 + 40*b0) + relu(z_t1 + 40*b1)
  int olo = wave_n * 32 + (lane & 15);
  float b00 = 40.f * bias[olo];
  float b01 = 40.f * bias[olo + 16];
  float b10 = 40.f * bias[OO + olo];
  float b11 = 40.f * bias[OO + olo + 16];
#pragma unroll
  for (int m = 0; m < 8; ++m) {
#pragma unroll
    for (int i = 0; i < 4; ++i) {
      int node = row0 + wave_m * 128 + m * 16 + (lane >> 4) * 4 + i;
      if (node < NN) {
        float r0 = fmaxf(acc[m][0][i] + b00, 0.f) + fmaxf(acc[m][2][i] + b10, 0.f);
        float r1 = fmaxf(acc[m][1][i] + b01, 0.f) + fmaxf(acc[m][3][i] + b11, 0.f);
        long base = (long)node * 1024 + kr * 128;
        __builtin_nontemporal_store(r0, out + base + olo);
        __builtin_nontemporal_store(r1, out + base + olo + 16);
      }
    }
  }
}

extern "C" void kernel_launch(void* const* d_in, const int* in_sizes, int n_in,
                              void* d_out, int out_size, void* d_ws, size_t ws_size,
                              hipStream_t stream) {
  const float* mesh   = (const float*)d_in[0];
  const float* bary_w = (const float*)d_in[1];
  const float* W      = (const float*)d_in[2];
  const float* bias   = (const float*)d_in[3];
  const float* coeffs = (const float*)d_in[4];
  const int* bidx     = (const int*)d_in[5];
  float* out = (float*)d_out;
  char* ws = (char*)d_ws;

  __hip_bfloat16* meshq = (__hip_bfloat16*)ws;                    // 12,800,000 B
  float* C2             = (float*)(ws + 12800000);                // 1,280 B
  __hip_bfloat16* BmatT = (__hip_bfloat16*)(ws + 12801280);       // 4,194,304 B
  __hip_bfloat16* Smat  = (__hip_bfloat16*)(ws + 16995584);       // 102,400,000 B
  unsigned* packb       = (unsigned*)(ws + 119395584);            // 24,000,000 B

  int do_pack = (ws_size >= 143395584UL) ? 1 : 0;

  prep_kernel<<<dim3(2048), dim3(256), 0, stream>>>(mesh, coeffs, W, bary_w, bidx,
                                                    meshq, C2, BmatT, packb, do_pack);
  if (do_pack) {
    for (int p = 0; p < 4; ++p)
      s_pass_packed<<<dim3(3125), dim3(256), 0, stream>>>(meshq, packb, C2, Smat, p);
  } else {
    for (int p = 0; p < 4; ++p)
      s_pass_kernel<<<dim3(3125), dim3(256), 0, stream>>>(meshq, bary_w, bidx, C2, Smat, p);
  }
  gemm_kernel<<<dim3(8, 200), dim3(512), 0, stream>>>(Smat, BmatT, bias, out);
}

// Round 6
// 430.566 us; speedup vs baseline: 1.0114x; 1.0114x over previous
//
#include <hip/hip_runtime.h>
#include <hip/hip_bf16.h>
#include <stdint.h>

#define NN 50000
#define RR 5
#define AA 8
#define FF 128
#define TT 2
#define OO 128
#define KDIM 1024   // A*F
#define NCOLS 2048  // 8 rotations * T * O
#define RA 40       // R*A

typedef __attribute__((ext_vector_type(8))) short short8;
typedef __attribute__((ext_vector_type(4))) float f32x4;
typedef __attribute__((ext_vector_type(4))) int i32x4;

__device__ inline void gload_lds16(const void* g, void* l) {
  __builtin_amdgcn_global_load_lds(
      (const __attribute__((address_space(1))) unsigned int*)g,
      (__attribute__((address_space(3))) unsigned int*)l, 16, 0, 0);
}

// ---------- prep: mesh->bf16 sliced, C2, BmatT, packed bary ----------
__global__ void prep_kernel(const float* __restrict__ mesh,
                            const float* __restrict__ coeffs,
                            const float* __restrict__ W,
                            const float* __restrict__ bary_w,
                            const int* __restrict__ bary_idx,
                            __hip_bfloat16* __restrict__ meshq,  // [4][N][32]
                            float* __restrict__ C2,
                            __hip_bfloat16* __restrict__ BmatT,
                            unsigned* __restrict__ packb,
                            int do_pack) {
  int tid = blockIdx.x * blockDim.x + threadIdx.x;
  int stride = gridDim.x * blockDim.x;
  for (int i = tid; i < NN * FF; i += stride) {
    int n = i >> 7, f = i & 127;
    int p = f >> 5, fo = f & 31;
    meshq[((long)p * NN + n) * 32 + fo] = __float2bfloat16(mesh[i]);
  }
  for (int i = tid; i < AA * RA; i += stride) {
    int a = i / RA, k = i % RA;
    float s = 0.f;
    for (int r = 0; r < RR; ++r) s += coeffs[(r * AA + a) * RA + k];
    C2[i] = s;
  }
  for (int i = tid; i < NCOLS * KDIM; i += stride) {
    int c = i >> 10, kf = i & 1023;
    int kr = c >> 8, t = (c >> 7) & 1, o = c & 127;
    int a = kf >> 7, f = kf & 127;
    int arot = (a + kr) & 7;
    BmatT[i] = __float2bfloat16(W[((arot * TT + t) * OO + o) * FF + f]);
  }
  if (do_pack) {
    for (int i = tid; i < NN * 120; i += stride) {
      __hip_bfloat16 h = __float2bfloat16(bary_w[i]);
      unsigned wb = *(unsigned short*)&h;
      packb[i] = ((unsigned)bary_idx[i] << 16) | wb;
    }
  }
}

// ---------- S pass (packed): gather 32-feature slice + C2 mixing ----------
__global__ __launch_bounds__(256) void s_pass_packed(
    const __hip_bfloat16* __restrict__ meshq,
    const unsigned* __restrict__ packb,
    const float* __restrict__ C2,
    __hip_bfloat16* __restrict__ Sout,
    int p) {
  __shared__ unsigned pk_s[16 * 120];
  __shared__ float c2_s[AA * RA];
  int tid = threadIdx.x;
  long n0 = (long)blockIdx.x * 16;
  const i32x4* psrc = (const i32x4*)(packb + n0 * 120);
  for (int i = tid; i < 480; i += 256) {
    i32x4 v = __builtin_nontemporal_load(psrc + i);
    ((i32x4*)pk_s)[i] = v;
  }
  for (int i = tid; i < AA * RA; i += 256) c2_s[i] = C2[i];
  __syncthreads();

  int g = tid >> 4;
  int fo = tid & 15;
  long n = n0 + g;
  const unsigned* pg = pk_s + g * 120;
  const char* mbase = (const char*)(meshq + (long)p * NN * 32) + fo * 4;

  float sx_acc[AA], sy_acc[AA];
#pragma unroll
  for (int a = 0; a < AA; ++a) { sx_acc[a] = 0.f; sy_acc[a] = 0.f; }

#pragma unroll 2
  for (int k = 0; k < RA; ++k) {
    float sx = 0.f, sy = 0.f;
#pragma unroll
    for (int j = 0; j < 3; ++j) {
      unsigned v = pg[k * 3 + j];
      unsigned row = v >> 16;
      float w = __uint_as_float(v << 16);
      unsigned u = *(const unsigned*)(mbase + (long)row * 64);
      sx += w * __uint_as_float(u << 16);
      sy += w * __uint_as_float(u & 0xffff0000u);
    }
#pragma unroll
    for (int a = 0; a < AA; ++a) {
      float c = c2_s[a * RA + k];
      sx_acc[a] += c * sx;
      sy_acc[a] += c * sy;
    }
  }

  long base = n * KDIM + p * 32 + fo * 2;
#pragma unroll
  for (int a = 0; a < AA; ++a) {
    __hip_bfloat16 hx = __float2bfloat16(sx_acc[a]);
    __hip_bfloat16 hy = __float2bfloat16(sy_acc[a]);
    unsigned u = (unsigned)*(unsigned short*)&hx | ((unsigned)*(unsigned short*)&hy << 16);
    __builtin_nontemporal_store(u, (unsigned*)(Sout + base + a * FF));
  }
}

// ---------- S pass (legacy fallback) ----------
__global__ __launch_bounds__(256) void s_pass_kernel(
    const __hip_bfloat16* __restrict__ meshq,
    const float* __restrict__ bary_w,
    const int* __restrict__ bary_idx,
    const float* __restrict__ C2,
    __hip_bfloat16* __restrict__ Sout,
    int p) {
  __shared__ float w_s[16 * 120];
  __shared__ int i_s[16 * 120];
  __shared__ float c2_s[AA * RA];
  int tid = threadIdx.x;
  long n0 = (long)blockIdx.x * 16;
  const f32x4* wsrc = (const f32x4*)(bary_w + n0 * 120);
  const i32x4* isrc = (const i32x4*)(bary_idx + n0 * 120);
  for (int i = tid; i < 480; i += 256) {
    f32x4 wv = __builtin_nontemporal_load(wsrc + i);
    ((f32x4*)w_s)[i] = wv;
    i32x4 iv = __builtin_nontemporal_load(isrc + i);
    ((i32x4*)i_s)[i] = iv;
  }
  for (int i = tid; i < AA * RA; i += 256) c2_s[i] = C2[i];
  __syncthreads();
  int g = tid >> 4;
  int fo = tid & 15;
  long n = n0 + g;
  const float* wg = w_s + g * 120;
  const int* ig = i_s + g * 120;
  const char* mbase = (const char*)(meshq + (long)p * NN * 32) + fo * 4;
  float sx_acc[AA], sy_acc[AA];
#pragma unroll
  for (int a = 0; a < AA; ++a) { sx_acc[a] = 0.f; sy_acc[a] = 0.f; }
#pragma unroll 2
  for (int k = 0; k < RA; ++k) {
    float sx = 0.f, sy = 0.f;
#pragma unroll
    for (int j = 0; j < 3; ++j) {
      int row = ig[k * 3 + j];
      unsigned u = *(const unsigned*)(mbase + (long)row * 64);
      float w = wg[k * 3 + j];
      sx += w * __uint_as_float(u << 16);
      sy += w * __uint_as_float(u & 0xffff0000u);
    }
#pragma unroll
    for (int a = 0; a < AA; ++a) {
      float c = c2_s[a * RA + k];
      sx_acc[a] += c * sx;
      sy_acc[a] += c * sy;
    }
  }
  long base = n * KDIM + p * 32 + fo * 2;
#pragma unroll
  for (int a = 0; a < AA; ++a) {
    __hip_bfloat16 hx = __float2bfloat16(sx_acc[a]);
    __hip_bfloat16 hy = __float2bfloat16(sy_acc[a]);
    unsigned u = (unsigned)*(unsigned short*)&hx | ((unsigned)*(unsigned short*)&hy << 16);
    __builtin_nontemporal_store(u, (unsigned*)(Sout + base + a * FF));
  }
}

// ---------- GEMM: 256x256 tile, BK=32, 4 LDS buffers, counted vmcnt,
// cross-step A-fragment register prefetch (pipelined: reads(s+1) overlap MFMA(s)) ----
// grid (8, 200): kr = by&7, mt = (by>>3)*8 + bx; 512 threads = 8 waves (2M x 4N)
__global__ __launch_bounds__(512, 2) void gemm_kernel(
    const __hip_bfloat16* __restrict__ Sm,
    const __hip_bfloat16* __restrict__ BT,
    const float* __restrict__ bias,
    float* __restrict__ out) {
  int bx = blockIdx.x;
  int by = blockIdx.y;
  int kr = by & 7;
  int mt = ((by >> 3) << 3) + bx;
  if (mt >= 196) return;
  int row0 = mt * 256;
  int col0 = kr * 256;

  int tid = threadIdx.x;
  int lane = tid & 63;
  int wid = tid >> 6;
  int wave_m = wid >> 2;   // 0..1
  int wave_n = wid & 3;    // 0..3

  // 4 buffers x (A 16KB + B 16KB). Row = 64B = 4 slots of 16B, slot ^= (r>>1)&3.
  __shared__ __align__(16) char lds[131072];

  long srcA[2], srcB[2];
  int dstA[2], dstB[2];
#pragma unroll
  for (int i = 0; i < 2; ++i) {
    int li = i * 512 + tid;
    int r = li >> 2, sp = li & 3;
    int sl = sp ^ ((r >> 1) & 3);
    int rowA = row0 + r;
    if (rowA >= NN) rowA = NN - 1;
    srcA[i] = (long)rowA * KDIM + sl * 8;
    dstA[i] = li * 16;
    srcB[i] = (long)(col0 + r) * KDIM + sl * 8;
    dstB[i] = 16384 + li * 16;
  }
  int offA[8], offB[4];
#pragma unroll
  for (int m = 0; m < 8; ++m) {
    int r = wave_m * 128 + m * 16 + (lane & 15);
    int phys = (lane >> 4) ^ ((r >> 1) & 3);
    offA[m] = r * 64 + phys * 16;
  }
#pragma unroll
  for (int q = 0; q < 4; ++q) {
    int c = (q >> 1) * 128 + wave_n * 32 + (q & 1) * 16 + (lane & 15);
    int phys = (lane >> 4) ^ ((c >> 1) & 3);
    offB[q] = 16384 + c * 64 + phys * 16;
  }

  f32x4 acc[8][4];
#pragma unroll
  for (int m = 0; m < 8; ++m)
#pragma unroll
    for (int q = 0; q < 4; ++q) acc[m][q] = (f32x4){0.f, 0.f, 0.f, 0.f};

#define STAGE_A(T)                                                   \
  {                                                                  \
    int b_ = ((T) & 3) * 32768;                                      \
    long k0_ = (long)(T) * 32;                                       \
    _Pragma("unroll") for (int i_ = 0; i_ < 2; ++i_)                 \
        gload_lds16(Sm + srcA[i_] + k0_, lds + b_ + dstA[i_]);       \
  }
#define STAGE_B(T)                                                   \
  {                                                                  \
    int b_ = ((T) & 3) * 32768;                                      \
    long k0_ = (long)(T) * 32;                                       \
    _Pragma("unroll") for (int i_ = 0; i_ < 2; ++i_)                 \
        gload_lds16(BT + srcB[i_] + k0_, lds + b_ + dstB[i_]);       \
  }

// One K-step. AC: A-frags for THIS step (loaded during previous step).
// AN: A-frags prefetched here for NEXT step (from buf (STP+1)&3).
// B-frags read in-step (short wait, covered by other wave's MFMAs).
#define GSTEP(STP, AC, AN, VMSTR, DOSTAGE, DOPREF, DOBAR)                     \
  {                                                                           \
    const char* cb_ = lds + ((STP) & 3) * 32768;                              \
    const char* nb_ = lds + (((STP) + 1) & 3) * 32768;                        \
    if (DOBAR) {                                                              \
      asm volatile("s_waitcnt " VMSTR ::: "memory");                          \
      __builtin_amdgcn_sched_barrier(0);                                      \
      __builtin_amdgcn_s_barrier();                                           \
      __builtin_amdgcn_sched_barrier(0);                                      \
    }                                                                         \
    short8 bC_[4];                                                            \
    _Pragma("unroll") for (int q_ = 0; q_ < 4; ++q_)                          \
        bC_[q_] = *(const short8*)(cb_ + offB[q_]);                           \
    if (DOPREF) {                                                             \
      _Pragma("unroll") for (int m_ = 0; m_ < 8; ++m_)                        \
          AN[m_] = *(const short8*)(nb_ + offA[m_]);                          \
    }                                                                         \
    if (DOSTAGE) { STAGE_A((STP) + 3) STAGE_B((STP) + 3) }                    \
    __builtin_amdgcn_sched_barrier(0);                                        \
    __builtin_amdgcn_s_setprio(1);                                            \
    _Pragma("unroll") for (int m_ = 0; m_ < 8; ++m_)                          \
        _Pragma("unroll") for (int q_ = 0; q_ < 4; ++q_)                      \
            acc[m_][q_] = __builtin_amdgcn_mfma_f32_16x16x32_bf16(            \
                AC[m_], bC_[q_], acc[m_][q_], 0, 0, 0);                       \
    __builtin_amdgcn_s_setprio(0);                                            \
    __builtin_amdgcn_sched_barrier(0);                                        \
  }

  short8 a0[8], a1[8];

  // prologue: stage 0..2; wait stage(0); prefetch A-frags of step 0 into a0
  STAGE_A(0) STAGE_B(0) STAGE_A(1) STAGE_B(1) STAGE_A(2) STAGE_B(2)
  asm volatile("s_waitcnt vmcnt(8)" ::: "memory");
  __builtin_amdgcn_sched_barrier(0);
  __builtin_amdgcn_s_barrier();
  __builtin_amdgcn_sched_barrier(0);
#pragma unroll
  for (int m = 0; m < 8; ++m) a0[m] = *(const short8*)(lds + offA[m]);

  for (int s2 = 0; s2 < 14; ++s2) {
    int s = s2 * 2;
    GSTEP(s, a0, a1, "vmcnt(4)", 1, 1, 1)
    GSTEP(s + 1, a1, a0, "vmcnt(4)", 1, 1, 1)
  }
  GSTEP(28, a0, a1, "vmcnt(4)", 1, 1, 1)   // stages buf(31)
  GSTEP(29, a1, a0, "vmcnt(4)", 0, 1, 1)
  GSTEP(30, a0, a1, "vmcnt(0)", 0, 1, 1)
  GSTEP(31, a1, a0, "vmcnt(0)", 0, 0, 0)

  // epilogue: out[n][kr][o] = relu(z_t0 + 40*b0) + relu(z_t1 + 40*b1)
  int olo = wave_n * 32 + (lane & 15);
  float b00 = 40.f * bias[olo];
  float b01 = 40.f * bias[olo + 16];
  float b10 = 40.f * bias[OO + olo];
  float b11 = 40.f * bias[OO + olo + 16];
#pragma unroll
  for (int m = 0; m < 8; ++m) {
#pragma unroll
    for (int i = 0; i < 4; ++i) {
      int node = row0 + wave_m * 128 + m * 16 + (lane >> 4) * 4 + i;
      if (node < NN) {
        float r0 = fmaxf(acc[m][0][i] + b00, 0.f) + fmaxf(acc[m][2][i] + b10, 0.f);
        float r1 = fmaxf(acc[m][1][i] + b01, 0.f) + fmaxf(acc[m][3][i] + b11, 0.f);
        long base = (long)node * 1024 + kr * 128;
        __builtin_nontemporal_store(r0, out + base + olo);
        __builtin_nontemporal_store(r1, out + base + olo + 16);
      }
    }
  }
}

extern "C" void kernel_launch(void* const* d_in, const int* in_sizes, int n_in,
                              void* d_out, int out_size, void* d_ws, size_t ws_size,
                              hipStream_t stream) {
  const float* mesh   = (const float*)d_in[0];
  const float* bary_w = (const float*)d_in[1];
  const float* W      = (const float*)d_in[2];
  const float* bias   = (const float*)d_in[3];
  const float* coeffs = (const float*)d_in[4];
  const int* bidx     = (const int*)d_in[5];
  float* out = (float*)d_out;
  char* ws = (char*)d_ws;

  __hip_bfloat16* meshq = (__hip_bfloat16*)ws;                    // 12,800,000 B
  float* C2             = (float*)(ws + 12800000);                // 1,280 B
  __hip_bfloat16* BmatT = (__hip_bfloat16*)(ws + 12801280);       // 4,194,304 B
  __hip_bfloat16* Smat  = (__hip_bfloat16*)(ws + 16995584);       // 102,400,000 B
  unsigned* packb       = (unsigned*)(ws + 119395584);            // 24,000,000 B

  int do_pack = (ws_size >= 143395584UL) ? 1 : 0;

  prep_kernel<<<dim3(2048), dim3(256), 0, stream>>>(mesh, coeffs, W, bary_w, bidx,
                                                    meshq, C2, BmatT, packb, do_pack);
  if (do_pack) {
    for (int p = 0; p < 4; ++p)
      s_pass_packed<<<dim3(3125), dim3(256), 0, stream>>>(meshq, packb, C2, Smat, p);
  } else {
    for (int p = 0; p < 4; ++p)
      s_pass_kernel<<<dim3(3125), dim3(256), 0, stream>>>(meshq, bary_w, bidx, C2, Smat, p);
  }
  gemm_kernel<<<dim3(8, 200), dim3(512), 0, stream>>>(Smat, BmatT, bias, out);
}